// Round 1
// baseline (751.018 us; speedup 1.0000x reference)
//
#include <hip/hip_runtime.h>
#include <stdint.h>

typedef __attribute__((ext_vector_type(8))) short s16x8;
typedef __attribute__((ext_vector_type(4))) float f32x4;

#define GLD_LDS16(gp, lp) __builtin_amdgcn_global_load_lds( \
    (__attribute__((address_space(1))) void*)(void*)(gp), \
    (__attribute__((address_space(3))) void*)(lp), 16, 0, 0)

__device__ __forceinline__ float b2f(unsigned short s) {
    unsigned int u = ((unsigned int)s) << 16;
    return __builtin_bit_cast(float, u);
}
__device__ __forceinline__ unsigned short f2b(float f) {
    unsigned int u = __builtin_bit_cast(unsigned int, f);
    u = (u + 0x7FFFu + ((u >> 16) & 1u)) >> 16;
    return (unsigned short)u;
}
__device__ __forceinline__ f32x4 mfma16(s16x8 a, s16x8 b, f32x4 c) {
    return __builtin_amdgcn_mfma_f32_16x16x32_bf16(a, b, c, 0, 0, 0);
}

// ---------------- RMSNorm (fp32 in -> bf16 out), D = 2048 ----------------
__global__ __launch_bounds__(256) void rmsnorm_bf16(
    const float* __restrict__ x, const float* __restrict__ wgt,
    unsigned short* __restrict__ out)
{
    const int row = blockIdx.x;
    const int t = threadIdx.x;
    const float* xr = x + (size_t)row * 2048;
    float4 a = *(const float4*)(xr + t * 8);
    float4 b = *(const float4*)(xr + t * 8 + 4);
    float ss = a.x*a.x + a.y*a.y + a.z*a.z + a.w*a.w
             + b.x*b.x + b.y*b.y + b.z*b.z + b.w*b.w;
    #pragma unroll
    for (int d = 1; d < 64; d <<= 1) ss += __shfl_xor(ss, d);
    __shared__ float red[4];
    if ((t & 63) == 0) red[t >> 6] = ss;
    __syncthreads();
    float tot = red[0] + red[1] + red[2] + red[3];
    float inv = rsqrtf(tot * (1.0f / 2048.0f) + 1e-5f);
    float vals[8] = {a.x, a.y, a.z, a.w, b.x, b.y, b.z, b.w};
    const float* wr_ = wgt + t * 8;
    s16x8 ov;
    #pragma unroll
    for (int j = 0; j < 8; ++j) ov[j] = (short)f2b(vals[j] * inv * wr_[j]);
    *(s16x8*)(out + (size_t)row * 2048 + t * 8) = ov;
}

// ------------- transpose + convert: in fp32 [K][N] -> out bf16 [N][K] -------------
__global__ __launch_bounds__(256) void transpose_to_bf16(
    const float* __restrict__ in, unsigned short* __restrict__ out, int K, int N)
{
    __shared__ float tile[32][33];
    int n0 = blockIdx.x * 32, k0 = blockIdx.y * 32;
    int r = threadIdx.x >> 5, c = threadIdx.x & 31;
    #pragma unroll
    for (int i = 0; i < 4; ++i)
        tile[r + i * 8][c] = in[(size_t)(k0 + r + i * 8) * N + n0 + c];
    __syncthreads();
    #pragma unroll
    for (int i = 0; i < 4; ++i)
        out[(size_t)(n0 + r + i * 8) * K + k0 + c] = f2b(tile[c][r + i * 8]);
}

// ---------------- GEMM: C[M,N] = A[M,K](bf16) * B[N,K]^T(bf16), 128x128x64 ----------------
// EPI 0: C bf16 plain.  EPI 1: C fp32 = acc + ADD.  EPI 2: C bf16 = silu(acc) * C_prev.
template <int EPI>
__global__ __launch_bounds__(256) void gemm_bt(
    const unsigned short* __restrict__ A,
    const unsigned short* __restrict__ B,
    void* __restrict__ Cv,
    const float* __restrict__ ADD,
    int N, int K)
{
    __shared__ unsigned short As[128 * 64];
    __shared__ unsigned short Bs[128 * 64];
    const int t = threadIdx.x;
    const int l = t & 63, w = t >> 6;
    const int wr = w >> 1, wc = w & 1;
    const int l15 = l & 15, lg = l >> 4;
    const int m0 = blockIdx.y * 128, n0 = blockIdx.x * 128;

    f32x4 acc[4][4] = {};

    const int row_l = t >> 3;          // 0..31
    const int col8 = (t & 7) * 8;
    const unsigned short* Ag = A + (size_t)(m0 + row_l) * K + col8;
    const unsigned short* Bg = B + (size_t)(n0 + row_l) * K + col8;
    unsigned short* Asd = As + t * 8;
    unsigned short* Bsd = Bs + t * 8;

    for (int kt = 0; kt < K; kt += 64) {
        __syncthreads();
        #pragma unroll
        for (int r = 0; r < 4; ++r) {
            GLD_LDS16(Ag + (size_t)(r * 32) * K + kt, Asd + r * 2048);
            GLD_LDS16(Bg + (size_t)(r * 32) * K + kt, Bsd + r * 2048);
        }
        __syncthreads();
        #pragma unroll
        for (int kk = 0; kk < 2; ++kk) {
            s16x8 af[4], bfr[4];
            #pragma unroll
            for (int i = 0; i < 4; ++i) {
                af[i]  = *(const s16x8*)(As + (wr * 64 + i * 16 + l15) * 64 + kk * 32 + lg * 8);
                bfr[i] = *(const s16x8*)(Bs + (wc * 64 + i * 16 + l15) * 64 + kk * 32 + lg * 8);
            }
            #pragma unroll
            for (int i = 0; i < 4; ++i)
                #pragma unroll
                for (int j = 0; j < 4; ++j)
                    acc[i][j] = mfma16(af[i], bfr[j], acc[i][j]);
        }
    }

    #pragma unroll
    for (int i = 0; i < 4; ++i) {
        #pragma unroll
        for (int r = 0; r < 4; ++r) {
            int row = m0 + wr * 64 + i * 16 + lg * 4 + r;
            size_t rb = (size_t)row * N;
            #pragma unroll
            for (int j = 0; j < 4; ++j) {
                int col = n0 + wc * 64 + j * 16 + l15;
                float v = acc[i][j][r];
                if constexpr (EPI == 0) {
                    ((unsigned short*)Cv)[rb + col] = f2b(v);
                } else if constexpr (EPI == 1) {
                    ((float*)Cv)[rb + col] = v + ADD[rb + col];
                } else {
                    unsigned short* Cb = (unsigned short*)Cv;
                    float y = b2f(Cb[rb + col]);
                    float sg = v / (1.0f + expf(-v));
                    Cb[rb + col] = f2b(sg * y);
                }
            }
        }
    }
}

// ---------------- RoPE table: [S][32] of (cos, sin) ----------------
__global__ void rope_tab_k(float2* __restrict__ tab) {
    int i = blockIdx.x * 256 + threadIdx.x;
    if (i >= 4096 * 32) return;
    int s = i >> 5, d = i & 31;
    // inv_freq = 10000^(-d/32) = 2^(-d/32 * log2(10000))
    float inv = exp2f(-(float)d * (13.287712379549449f / 32.0f));
    float fr = (float)s * inv;
    float sv, cv;
    sincosf(fr, &sv, &cv);
    tab[i] = make_float2(cv, sv);
}

// ---------------- RoPE apply (in-place on qkv, q heads + k heads) ----------------
__global__ void rope_apply_k(unsigned short* __restrict__ qkv, const float2* __restrict__ tab) {
    int i = blockIdx.x * 256 + threadIdx.x;
    if (i >= 4096 * 40 * 4) return;
    int dg = i & 3;
    int rest = i >> 2;
    int head = rest % 40;
    int s = rest / 40;
    int off = head < 32 ? head * 64 : 2048 + (head - 32) * 64;
    unsigned short* p = qkv + (size_t)s * 3072 + off + dg * 8;
    s16x8 x1 = *(const s16x8*)p;
    s16x8 x2 = *(const s16x8*)(p + 32);
    const float2* tb = tab + s * 32 + dg * 8;
    s16x8 o1, o2;
    #pragma unroll
    for (int j = 0; j < 8; ++j) {
        float2 cs = tb[j];
        float a = b2f((unsigned short)x1[j]);
        float b = b2f((unsigned short)x2[j]);
        o1[j] = (short)f2b(a * cs.x - b * cs.y);
        o2[j] = (short)f2b(b * cs.x + a * cs.y);
    }
    *(s16x8*)p = o1;
    *(s16x8*)(p + 32) = o2;
}

// ---------------- Sliding-window attention, flash-style ----------------
// grid (S/64, H); 4 waves; wave w owns 16 query rows. Window: k<=q, q-k<512.
__global__ __launch_bounds__(256) void attn_swa(
    const unsigned short* __restrict__ qkv,
    unsigned short* __restrict__ out)
{
    constexpr int LDQ = 3072;
    const int qb = blockIdx.x;
    const int h = blockIdx.y;
    const int kvh = h >> 2;
    const int q0 = qb * 64;
    const int t = threadIdx.x, l = t & 63, w = t >> 6;
    const int l15 = l & 15, lg = l >> 4;

    __shared__ unsigned short Kl[64 * 64];   // [key][hd]
    __shared__ unsigned short Vt[64 * 72];   // [hd][key], padded ld=72
    __shared__ unsigned short Pl[4 * 16 * 72]; // per-wave P [16 q][64 key], ld=72

    s16x8 qf[2];
    {
        const unsigned short* qp = qkv + (size_t)(q0 + w * 16 + l15) * LDQ + h * 64 + lg * 8;
        qf[0] = *(const s16x8*)(qp);
        qf[1] = *(const s16x8*)(qp + 32);
    }
    float m_run[4] = {-1e30f, -1e30f, -1e30f, -1e30f};
    float l_run[4] = {0.f, 0.f, 0.f, 0.f};
    f32x4 o[4] = {};

    const float SC = 0.0625f * 1.4426950408889634f;  // (PRE^2/sqrt(HD)) * log2(e)
    const int kt_lo = qb >= 8 ? qb - 8 : 0;

    for (int kt = kt_lo; kt <= qb; ++kt) {
        const int ks = kt * 64;
        __syncthreads();
        {   // stage K tile [64][64] linearly via global_load_lds
            const unsigned short* kg = qkv + (size_t)(ks + (t >> 3)) * LDQ + 2048 + kvh * 64 + (t & 7) * 8;
            GLD_LDS16(kg, Kl + t * 8);
            GLD_LDS16(kg + (size_t)32 * LDQ, Kl + t * 8 + 2048);
        }
        {   // stage V transposed: wave w writes hd rows [w*16, w*16+16), lane l = key
            const unsigned short* vg = qkv + (size_t)(ks + l) * LDQ + 2560 + kvh * 64 + w * 16;
            s16x8 v0 = *(const s16x8*)vg;
            s16x8 v1 = *(const s16x8*)(vg + 8);
            #pragma unroll
            for (int j = 0; j < 8; ++j) Vt[(w * 16 + j) * 72 + l] = (unsigned short)v0[j];
            #pragma unroll
            for (int j = 0; j < 8; ++j) Vt[(w * 16 + 8 + j) * 72 + l] = (unsigned short)v1[j];
        }
        __syncthreads();

        // S = Q K^T : 4 key-fragments of 16
        f32x4 sf[4] = {};
        #pragma unroll
        for (int kf = 0; kf < 4; ++kf) {
            #pragma unroll
            for (int kk = 0; kk < 2; ++kk) {
                s16x8 kb = *(const s16x8*)(Kl + (kf * 16 + l15) * 64 + kk * 32 + lg * 8);
                sf[kf] = mfma16(qf[kk], kb, sf[kf]);
            }
        }

        // masked row max
        float tmax[4];
        #pragma unroll
        for (int r = 0; r < 4; ++r) {
            int qrow = q0 + w * 16 + lg * 4 + r;
            float mx = -1e30f;
            #pragma unroll
            for (int kf = 0; kf < 4; ++kf) {
                int key = ks + kf * 16 + l15;
                bool valid = (key <= qrow) && (qrow - key < 512);
                if (valid) mx = fmaxf(mx, sf[kf][r]);
            }
            #pragma unroll
            for (int d2 = 1; d2 < 16; d2 <<= 1) mx = fmaxf(mx, __shfl_xor(mx, d2));
            tmax[r] = mx;
        }

        float alpha[4], rsum[4];
        #pragma unroll
        for (int r = 0; r < 4; ++r) {
            float mnew = fmaxf(m_run[r], tmax[r]);
            alpha[r] = exp2f((m_run[r] - mnew) * SC);
            m_run[r] = mnew;
            rsum[r] = 0.f;
        }

        unsigned short* Pw = Pl + w * (16 * 72);
        #pragma unroll
        for (int kf = 0; kf < 4; ++kf) {
            #pragma unroll
            for (int r = 0; r < 4; ++r) {
                int qrow = q0 + w * 16 + lg * 4 + r;
                int key = ks + kf * 16 + l15;
                bool valid = (key <= qrow) && (qrow - key < 512);
                float p = valid ? exp2f((sf[kf][r] - m_run[r]) * SC) : 0.f;
                rsum[r] += p;
                Pw[(lg * 4 + r) * 72 + kf * 16 + l15] = f2b(p);
            }
        }
        #pragma unroll
        for (int r = 0; r < 4; ++r) {
            #pragma unroll
            for (int d2 = 1; d2 < 16; d2 <<= 1) rsum[r] += __shfl_xor(rsum[r], d2);
            l_run[r] = l_run[r] * alpha[r] + rsum[r];
        }
        #pragma unroll
        for (int hf = 0; hf < 4; ++hf)
            #pragma unroll
            for (int r = 0; r < 4; ++r) o[hf][r] *= alpha[r];

        asm volatile("s_waitcnt lgkmcnt(0)" ::: "memory");
        __builtin_amdgcn_sched_barrier(0);

        // O += P V
        #pragma unroll
        for (int kk2 = 0; kk2 < 2; ++kk2) {
            s16x8 pa = *(const s16x8*)(Pw + l15 * 72 + kk2 * 32 + lg * 8);
            #pragma unroll
            for (int hf = 0; hf < 4; ++hf) {
                s16x8 vb = *(const s16x8*)(Vt + (hf * 16 + l15) * 72 + kk2 * 32 + lg * 8);
                o[hf] = mfma16(pa, vb, o[hf]);
            }
        }
    }

    #pragma unroll
    for (int r = 0; r < 4; ++r) {
        int qrow = q0 + w * 16 + lg * 4 + r;
        float invl = 1.0f / l_run[r];
        unsigned short* orow = out + (size_t)qrow * 2048 + h * 64;
        #pragma unroll
        for (int hf = 0; hf < 4; ++hf)
            orow[hf * 16 + l15] = f2b(o[hf][r] * invl);
    }
}

extern "C" void kernel_launch(void* const* d_in, const int* in_sizes, int n_in,
                              void* d_out, int out_size, void* d_ws, size_t ws_size,
                              hipStream_t stream)
{
    const float* hidden = (const float*)d_in[0];
    const float* w_mix  = (const float*)d_in[1];
    const float* wq     = (const float*)d_in[2];
    const float* wk     = (const float*)d_in[3];
    const float* wv     = (const float*)d_in[4];
    const float* wo     = (const float*)d_in[5];
    const float* w_mlp  = (const float*)d_in[6];
    const float* wg     = (const float*)d_in[7];
    const float* wd     = (const float*)d_in[8];
    float* out = (float*)d_out;

    char* ws = (char*)d_ws;
    size_t off = 0;
    auto alloc = [&](size_t bytes) {
        char* p = ws + off;
        off += (bytes + 255) & ~(size_t)255;
        return p;
    };
    unsigned short* Wt   = (unsigned short*)alloc((size_t)11264 * 2048 * 2); // shared weight^T region
    unsigned short* xn   = (unsigned short*)alloc((size_t)4096 * 2048 * 2);  // normed acts (reused)
    unsigned short* qkv  = (unsigned short*)alloc((size_t)4096 * 3072 * 2);
    float2*         rtab = (float2*)alloc((size_t)4096 * 32 * 8);
    unsigned short* attn = (unsigned short*)alloc((size_t)4096 * 2048 * 2);
    float*          hbuf = (float*)alloc((size_t)4096 * 2048 * 4);
    unsigned short* act  = (unsigned short*)alloc((size_t)4096 * 5632 * 2);

    // 1. x = rmsnorm(hidden) -> bf16  (PRE_SCALE folded into attention softmax scale)
    rmsnorm_bf16<<<4096, 256, 0, stream>>>(hidden, w_mix, xn);

    // 2. W^T for q,k,v concatenated: rows [0,2048)=wq^T, [2048,2560)=wk^T, [2560,3072)=wv^T
    transpose_to_bf16<<<dim3(64, 64), 256, 0, stream>>>(wq, Wt, 2048, 2048);
    transpose_to_bf16<<<dim3(16, 64), 256, 0, stream>>>(wk, Wt + (size_t)2048 * 2048, 2048, 512);
    transpose_to_bf16<<<dim3(16, 64), 256, 0, stream>>>(wv, Wt + (size_t)2560 * 2048, 2048, 512);

    // 3. qkv = x @ [wq|wk|wv]
    gemm_bt<0><<<dim3(24, 32), 256, 0, stream>>>(xn, Wt, qkv, nullptr, 3072, 2048);

    // 4. RoPE on q and k heads
    rope_tab_k<<<(4096 * 32 + 255) / 256, 256, 0, stream>>>(rtab);
    rope_apply_k<<<(4096 * 40 * 4 + 255) / 256, 256, 0, stream>>>(qkv, rtab);

    // 5. sliding-window attention
    attn_swa<<<dim3(64, 32), 256, 0, stream>>>(qkv, attn);

    // 6. h = hidden + attn @ wo
    transpose_to_bf16<<<dim3(64, 64), 256, 0, stream>>>(wo, Wt, 2048, 2048);
    gemm_bt<1><<<dim3(16, 32), 256, 0, stream>>>(attn, Wt, hbuf, hidden, 2048, 2048);

    // 7. xn2 = rmsnorm(h)
    rmsnorm_bf16<<<4096, 256, 0, stream>>>(hbuf, w_mlp, xn);

    // 8. MLP: act = y; act = silu(gate) * act
    transpose_to_bf16<<<dim3(352, 64), 256, 0, stream>>>(wg, Wt, 2048, 11264);
    gemm_bt<0><<<dim3(44, 32), 256, 0, stream>>>(xn, Wt + (size_t)5632 * 2048, act, nullptr, 5632, 2048);
    gemm_bt<2><<<dim3(44, 32), 256, 0, stream>>>(xn, Wt, act, nullptr, 5632, 2048);

    // 9. out = h + act @ w_down
    transpose_to_bf16<<<dim3(64, 176), 256, 0, stream>>>(wd, Wt, 5632, 2048);
    gemm_bt<1><<<dim3(16, 32), 256, 0, stream>>>(act, Wt, out, hbuf, 2048, 5632);
}

// Round 2
// 702.938 us; speedup vs baseline: 1.0684x; 1.0684x over previous
//
#include <hip/hip_runtime.h>
#include <stdint.h>

typedef __attribute__((ext_vector_type(8))) short s16x8;
typedef __attribute__((ext_vector_type(4))) float f32x4;

#define GLD_LDS16(gp, lp) __builtin_amdgcn_global_load_lds( \
    (__attribute__((address_space(1))) void*)(void*)(gp), \
    (__attribute__((address_space(3))) void*)(lp), 16, 0, 0)

__device__ __forceinline__ float b2f(unsigned short s) {
    unsigned int u = ((unsigned int)s) << 16;
    return __builtin_bit_cast(float, u);
}
__device__ __forceinline__ unsigned short f2b(float f) {
    unsigned int u = __builtin_bit_cast(unsigned int, f);
    u = (u + 0x7FFFu + ((u >> 16) & 1u)) >> 16;
    return (unsigned short)u;
}
__device__ __forceinline__ f32x4 mfma16(s16x8 a, s16x8 b, f32x4 c) {
    return __builtin_amdgcn_mfma_f32_16x16x32_bf16(a, b, c, 0, 0, 0);
}

// ---------------- RMSNorm (fp32 in -> bf16 out), D = 2048 ----------------
__global__ __launch_bounds__(256) void rmsnorm_bf16(
    const float* __restrict__ x, const float* __restrict__ wgt,
    unsigned short* __restrict__ out)
{
    const int row = blockIdx.x;
    const int t = threadIdx.x;
    const float* xr = x + (size_t)row * 2048;
    float4 a = *(const float4*)(xr + t * 8);
    float4 b = *(const float4*)(xr + t * 8 + 4);
    float ss = a.x*a.x + a.y*a.y + a.z*a.z + a.w*a.w
             + b.x*b.x + b.y*b.y + b.z*b.z + b.w*b.w;
    #pragma unroll
    for (int d = 1; d < 64; d <<= 1) ss += __shfl_xor(ss, d);
    __shared__ float red[4];
    if ((t & 63) == 0) red[t >> 6] = ss;
    __syncthreads();
    float tot = red[0] + red[1] + red[2] + red[3];
    float inv = rsqrtf(tot * (1.0f / 2048.0f) + 1e-5f);
    float vals[8] = {a.x, a.y, a.z, a.w, b.x, b.y, b.z, b.w};
    const float* wr_ = wgt + t * 8;
    s16x8 ov;
    #pragma unroll
    for (int j = 0; j < 8; ++j) ov[j] = (short)f2b(vals[j] * inv * wr_[j]);
    *(s16x8*)(out + (size_t)row * 2048 + t * 8) = ov;
}

// ------------- transpose + convert: in fp32 [K][N] -> out bf16 [N][K] -------------
__global__ __launch_bounds__(256) void transpose_to_bf16(
    const float* __restrict__ in, unsigned short* __restrict__ out, int K, int N)
{
    __shared__ float tile[32][33];
    int n0 = blockIdx.x * 32, k0 = blockIdx.y * 32;
    int r = threadIdx.x >> 5, c = threadIdx.x & 31;
    #pragma unroll
    for (int i = 0; i < 4; ++i)
        tile[r + i * 8][c] = in[(size_t)(k0 + r + i * 8) * N + n0 + c];
    __syncthreads();
    #pragma unroll
    for (int i = 0; i < 4; ++i)
        out[(size_t)(n0 + r + i * 8) * K + k0 + c] = f2b(tile[c][r + i * 8]);
}

// ---------------- 8-phase GEMM: C[4096,N] = A[4096,K](bf16) * B[N,K]^T(bf16) ----------------
// Tile BM x 256, BK=64 as two K-half sub-tiles [rows][32]; 4 slots per operand
// (3-phase prefetch pipeline, counted vmcnt, never drained to 0 in the loop).
// EPI 0: C bf16.  EPI 1: C fp32 = acc + ADD.  EPI 2: C bf16 = silu(acc) * C_prev.
template <int BM, int EPI>
__global__ __launch_bounds__(512, 2) void gemm8p(
    const unsigned short* __restrict__ A,
    const unsigned short* __restrict__ B,
    void* __restrict__ Cv,
    const float* __restrict__ ADD,
    int N, int K)
{
    constexpr int MT = 4096 / BM;                 // M tiles
    constexpr int NJ = (BM == 256) ? 4 : 2;       // per-wave N fragments
    constexpr int ASUB = BM * 32;                 // elems per A sub-tile
    constexpr int BSUB = 256 * 32;
    __shared__ __align__(16) unsigned short As[4 * ASUB];
    __shared__ __align__(16) unsigned short Bs[4 * BSUB];

    const int t = threadIdx.x;
    const int l = t & 63, w = t >> 6;
    const int l15 = l & 15, lg = l >> 4;
    const int wr = (BM == 256) ? (w >> 2) : 0;
    const int wc = (BM == 256) ? (w & 3) : w;
    const int wcb = wc * (256 / ((BM == 256) ? 4 : 8));

    // bijective XCD-aware block swizzle (m204)
    const int nwg = (int)gridDim.x;
    const int orig = (int)blockIdx.x;
    const int q8 = nwg >> 3, r8 = nwg & 7;
    const int xcd = orig & 7, lid = orig >> 3;
    const int wg = (xcd < r8 ? xcd * (q8 + 1) : r8 * (q8 + 1) + (xcd - r8) * q8) + lid;
    const int m0 = (wg % MT) * BM;
    const int n0 = (wg / MT) * 256;

    f32x4 acc[8][NJ] = {};

    int aoff[8], boff[NJ];
    #pragma unroll
    for (int i = 0; i < 8; ++i) aoff[i] = (wr * 128 + i * 16 + l15) * 32 + lg * 8;
    #pragma unroll
    for (int j = 0; j < NJ; ++j) boff[j] = (wcb + j * 16 + l15) * 32 + lg * 8;

    const int srow = t >> 2, scol = (t & 3) * 8;  // staging row/col within sub-tile

    auto stage = [&](int slot, int koff) {
        #pragma unroll
        for (int q2 = 0; q2 < BM / 128; ++q2)
            GLD_LDS16(A + (size_t)(m0 + q2 * 128 + srow) * K + koff + scol,
                      &As[slot * ASUB + q2 * 4096 + t * 8]);
        #pragma unroll
        for (int q2 = 0; q2 < 2; ++q2)
            GLD_LDS16(B + (size_t)(n0 + q2 * 128 + srow) * K + koff + scol,
                      &Bs[slot * BSUB + q2 * 4096 + t * 8]);
    };
    auto waitv = [&]() {
        if constexpr (BM == 256) asm volatile("s_waitcnt vmcnt(8)" ::: "memory");
        else                     asm volatile("s_waitcnt vmcnt(6)" ::: "memory");
    };

    // prologue: slots 0,1,2 <- phase 0,1,2 data; wait for slot 0 only
    stage(0, 0); stage(1, 32); stage(2, 64);
    waitv();
    __builtin_amdgcn_s_barrier();

    const int PH = K / 32;           // phases (K%128==0 for all our shapes)
    const int kmax = K - 32;

    for (int p0 = 0; p0 < PH; p0 += 4) {
        #pragma unroll
        for (int pp = 0; pp < 4; ++pp) {
            const int sR = pp, sW = (pp + 3) & 3;
            int kW = (p0 + pp + 3) * 32; if (kW > kmax) kW = kmax;  // tail: dummy reload
            s16x8 af[8], bfv[NJ];
            #pragma unroll
            for (int i = 0; i < 8; ++i)
                af[i] = *(const s16x8*)&As[sR * ASUB + aoff[i]];
            #pragma unroll
            for (int j = 0; j < NJ; ++j)
                bfv[j] = *(const s16x8*)&Bs[sR * BSUB + boff[j]];
            stage(sW, kW);
            waitv();                                   // retire data for phase p+1
            asm volatile("s_waitcnt lgkmcnt(0)" ::: "memory");
            __builtin_amdgcn_sched_barrier(0);
            __builtin_amdgcn_s_setprio(1);
            #pragma unroll
            for (int i = 0; i < 8; ++i)
                #pragma unroll
                for (int j = 0; j < NJ; ++j)
                    acc[i][j] = mfma16(af[i], bfv[j], acc[i][j]);
            __builtin_amdgcn_s_setprio(0);
            __builtin_amdgcn_sched_barrier(0);
            __builtin_amdgcn_s_barrier();
        }
    }

    #pragma unroll
    for (int i = 0; i < 8; ++i) {
        #pragma unroll
        for (int r = 0; r < 4; ++r) {
            const int row = m0 + wr * 128 + i * 16 + lg * 4 + r;
            const size_t rb = (size_t)row * N;
            #pragma unroll
            for (int j = 0; j < NJ; ++j) {
                const int col = n0 + wcb + j * 16 + l15;
                float v = acc[i][j][r];
                if constexpr (EPI == 0) {
                    ((unsigned short*)Cv)[rb + col] = f2b(v);
                } else if constexpr (EPI == 1) {
                    ((float*)Cv)[rb + col] = v + ADD[rb + col];
                } else {
                    unsigned short* Cb = (unsigned short*)Cv;
                    float y = b2f(Cb[rb + col]);
                    float sg = v / (1.0f + expf(-v));
                    Cb[rb + col] = f2b(sg * y);
                }
            }
        }
    }
}

// ---------------- RoPE table: [S][32] of (cos, sin) ----------------
__global__ void rope_tab_k(float2* __restrict__ tab) {
    int i = blockIdx.x * 256 + threadIdx.x;
    if (i >= 4096 * 32) return;
    int s = i >> 5, d = i & 31;
    float inv = exp2f(-(float)d * (13.287712379549449f / 32.0f));
    float fr = (float)s * inv;
    float sv, cv;
    sincosf(fr, &sv, &cv);
    tab[i] = make_float2(cv, sv);
}

// ---------------- RoPE apply (in-place on qkv, q heads + k heads) ----------------
__global__ void rope_apply_k(unsigned short* __restrict__ qkv, const float2* __restrict__ tab) {
    int i = blockIdx.x * 256 + threadIdx.x;
    if (i >= 4096 * 40 * 4) return;
    int dg = i & 3;
    int rest = i >> 2;
    int head = rest % 40;
    int s = rest / 40;
    int off = head < 32 ? head * 64 : 2048 + (head - 32) * 64;
    unsigned short* p = qkv + (size_t)s * 3072 + off + dg * 8;
    s16x8 x1 = *(const s16x8*)p;
    s16x8 x2 = *(const s16x8*)(p + 32);
    const float2* tb = tab + s * 32 + dg * 8;
    s16x8 o1, o2;
    #pragma unroll
    for (int j = 0; j < 8; ++j) {
        float2 cs = tb[j];
        float a = b2f((unsigned short)x1[j]);
        float b = b2f((unsigned short)x2[j]);
        o1[j] = (short)f2b(a * cs.x - b * cs.y);
        o2[j] = (short)f2b(b * cs.x + a * cs.y);
    }
    *(s16x8*)p = o1;
    *(s16x8*)(p + 32) = o2;
}

// ---------------- Sliding-window attention, flash-style ----------------
__global__ __launch_bounds__(256) void attn_swa(
    const unsigned short* __restrict__ qkv,
    unsigned short* __restrict__ out)
{
    constexpr int LDQ = 3072;
    const int qb = blockIdx.x;
    const int h = blockIdx.y;
    const int kvh = h >> 2;
    const int q0 = qb * 64;
    const int t = threadIdx.x, l = t & 63, w = t >> 6;
    const int l15 = l & 15, lg = l >> 4;

    __shared__ unsigned short Kl[64 * 64];
    __shared__ unsigned short Vt[64 * 72];
    __shared__ unsigned short Pl[4 * 16 * 72];

    s16x8 qf[2];
    {
        const unsigned short* qp = qkv + (size_t)(q0 + w * 16 + l15) * LDQ + h * 64 + lg * 8;
        qf[0] = *(const s16x8*)(qp);
        qf[1] = *(const s16x8*)(qp + 32);
    }
    float m_run[4] = {-1e30f, -1e30f, -1e30f, -1e30f};
    float l_run[4] = {0.f, 0.f, 0.f, 0.f};
    f32x4 o[4] = {};

    const float SC = 0.0625f * 1.4426950408889634f;
    const int kt_lo = qb >= 8 ? qb - 8 : 0;

    for (int kt = kt_lo; kt <= qb; ++kt) {
        const int ks = kt * 64;
        __syncthreads();
        {
            const unsigned short* kg = qkv + (size_t)(ks + (t >> 3)) * LDQ + 2048 + kvh * 64 + (t & 7) * 8;
            GLD_LDS16(kg, Kl + t * 8);
            GLD_LDS16(kg + (size_t)32 * LDQ, Kl + t * 8 + 2048);
        }
        {
            const unsigned short* vg = qkv + (size_t)(ks + l) * LDQ + 2560 + kvh * 64 + w * 16;
            s16x8 v0 = *(const s16x8*)vg;
            s16x8 v1 = *(const s16x8*)(vg + 8);
            #pragma unroll
            for (int j = 0; j < 8; ++j) Vt[(w * 16 + j) * 72 + l] = (unsigned short)v0[j];
            #pragma unroll
            for (int j = 0; j < 8; ++j) Vt[(w * 16 + 8 + j) * 72 + l] = (unsigned short)v1[j];
        }
        __syncthreads();

        f32x4 sf[4] = {};
        #pragma unroll
        for (int kf = 0; kf < 4; ++kf) {
            #pragma unroll
            for (int kk = 0; kk < 2; ++kk) {
                s16x8 kb = *(const s16x8*)(Kl + (kf * 16 + l15) * 64 + kk * 32 + lg * 8);
                sf[kf] = mfma16(qf[kk], kb, sf[kf]);
            }
        }

        float tmax[4];
        #pragma unroll
        for (int r = 0; r < 4; ++r) {
            int qrow = q0 + w * 16 + lg * 4 + r;
            float mx = -1e30f;
            #pragma unroll
            for (int kf = 0; kf < 4; ++kf) {
                int key = ks + kf * 16 + l15;
                bool valid = (key <= qrow) && (qrow - key < 512);
                if (valid) mx = fmaxf(mx, sf[kf][r]);
            }
            #pragma unroll
            for (int d2 = 1; d2 < 16; d2 <<= 1) mx = fmaxf(mx, __shfl_xor(mx, d2));
            tmax[r] = mx;
        }

        float alpha[4], rsum[4];
        #pragma unroll
        for (int r = 0; r < 4; ++r) {
            float mnew = fmaxf(m_run[r], tmax[r]);
            alpha[r] = exp2f((m_run[r] - mnew) * SC);
            m_run[r] = mnew;
            rsum[r] = 0.f;
        }

        unsigned short* Pw = Pl + w * (16 * 72);
        #pragma unroll
        for (int kf = 0; kf < 4; ++kf) {
            #pragma unroll
            for (int r = 0; r < 4; ++r) {
                int qrow = q0 + w * 16 + lg * 4 + r;
                int key = ks + kf * 16 + l15;
                bool valid = (key <= qrow) && (qrow - key < 512);
                float p = valid ? exp2f((sf[kf][r] - m_run[r]) * SC) : 0.f;
                rsum[r] += p;
                Pw[(lg * 4 + r) * 72 + kf * 16 + l15] = f2b(p);
            }
        }
        #pragma unroll
        for (int r = 0; r < 4; ++r) {
            #pragma unroll
            for (int d2 = 1; d2 < 16; d2 <<= 1) rsum[r] += __shfl_xor(rsum[r], d2);
            l_run[r] = l_run[r] * alpha[r] + rsum[r];
        }
        #pragma unroll
        for (int hf = 0; hf < 4; ++hf)
            #pragma unroll
            for (int r = 0; r < 4; ++r) o[hf][r] *= alpha[r];

        asm volatile("s_waitcnt lgkmcnt(0)" ::: "memory");
        __builtin_amdgcn_sched_barrier(0);

        #pragma unroll
        for (int kk2 = 0; kk2 < 2; ++kk2) {
            s16x8 pa = *(const s16x8*)(Pw + l15 * 72 + kk2 * 32 + lg * 8);
            #pragma unroll
            for (int hf = 0; hf < 4; ++hf) {
                s16x8 vb = *(const s16x8*)(Vt + (hf * 16 + l15) * 72 + kk2 * 32 + lg * 8);
                o[hf] = mfma16(pa, vb, o[hf]);
            }
        }
    }

    #pragma unroll
    for (int r = 0; r < 4; ++r) {
        int qrow = q0 + w * 16 + lg * 4 + r;
        float invl = 1.0f / l_run[r];
        unsigned short* orow = out + (size_t)qrow * 2048 + h * 64;
        #pragma unroll
        for (int hf = 0; hf < 4; ++hf)
            orow[hf * 16 + l15] = f2b(o[hf][r] * invl);
    }
}

extern "C" void kernel_launch(void* const* d_in, const int* in_sizes, int n_in,
                              void* d_out, int out_size, void* d_ws, size_t ws_size,
                              hipStream_t stream)
{
    const float* hidden = (const float*)d_in[0];
    const float* w_mix  = (const float*)d_in[1];
    const float* wq     = (const float*)d_in[2];
    const float* wk     = (const float*)d_in[3];
    const float* wv     = (const float*)d_in[4];
    const float* wo     = (const float*)d_in[5];
    const float* w_mlp  = (const float*)d_in[6];
    const float* wg     = (const float*)d_in[7];
    const float* wd     = (const float*)d_in[8];
    float* out = (float*)d_out;

    char* ws = (char*)d_ws;
    size_t off = 0;
    auto alloc = [&](size_t bytes) {
        char* p = ws + off;
        off += (bytes + 255) & ~(size_t)255;
        return p;
    };
    unsigned short* Wt   = (unsigned short*)alloc((size_t)11264 * 2048 * 2);
    unsigned short* xn   = (unsigned short*)alloc((size_t)4096 * 2048 * 2);
    unsigned short* qkv  = (unsigned short*)alloc((size_t)4096 * 3072 * 2);
    float2*         rtab = (float2*)alloc((size_t)4096 * 32 * 8);
    unsigned short* attn = (unsigned short*)alloc((size_t)4096 * 2048 * 2);
    float*          hbuf = (float*)alloc((size_t)4096 * 2048 * 4);
    unsigned short* act  = (unsigned short*)alloc((size_t)4096 * 5632 * 2);

    // 1. x = rmsnorm(hidden) -> bf16
    rmsnorm_bf16<<<4096, 256, 0, stream>>>(hidden, w_mix, xn);

    // 2. W^T for q,k,v concatenated
    transpose_to_bf16<<<dim3(64, 64), 256, 0, stream>>>(wq, Wt, 2048, 2048);
    transpose_to_bf16<<<dim3(16, 64), 256, 0, stream>>>(wk, Wt + (size_t)2048 * 2048, 2048, 512);
    transpose_to_bf16<<<dim3(16, 64), 256, 0, stream>>>(wv, Wt + (size_t)2560 * 2048, 2048, 512);

    // 3. qkv = x @ [wq|wk|wv]   (M=4096, N=3072, K=2048) BM=256 -> 192 blocks
    gemm8p<256, 0><<<192, 512, 0, stream>>>(xn, Wt, qkv, nullptr, 3072, 2048);

    // 4. RoPE
    rope_tab_k<<<(4096 * 32 + 255) / 256, 256, 0, stream>>>(rtab);
    rope_apply_k<<<(4096 * 40 * 4 + 255) / 256, 256, 0, stream>>>(qkv, rtab);

    // 5. sliding-window attention
    attn_swa<<<dim3(64, 32), 256, 0, stream>>>(qkv, attn);

    // 6. h = hidden + attn @ wo   (N=2048) BM=128 -> 256 blocks (full grid)
    transpose_to_bf16<<<dim3(64, 64), 256, 0, stream>>>(wo, Wt, 2048, 2048);
    gemm8p<128, 1><<<256, 512, 0, stream>>>(attn, Wt, hbuf, hidden, 2048, 2048);

    // 7. xn2 = rmsnorm(h)
    rmsnorm_bf16<<<4096, 256, 0, stream>>>(hbuf, w_mlp, xn);

    // 8. MLP: act = y; act = silu(gate) * act   (N=5632) BM=128 -> 704 blocks
    transpose_to_bf16<<<dim3(352, 64), 256, 0, stream>>>(wg, Wt, 2048, 11264);
    gemm8p<128, 0><<<704, 512, 0, stream>>>(xn, Wt + (size_t)5632 * 2048, act, nullptr, 5632, 2048);
    gemm8p<128, 2><<<704, 512, 0, stream>>>(xn, Wt, act, nullptr, 5632, 2048);

    // 9. out = h + act @ w_down   (N=2048, K=5632) BM=128 -> 256 blocks
    transpose_to_bf16<<<dim3(64, 176), 256, 0, stream>>>(wd, Wt, 5632, 2048);
    gemm8p<128, 1><<<256, 512, 0, stream>>>(act, Wt, out, hbuf, 2048, 5632);
}

// Round 3
// 669.238 us; speedup vs baseline: 1.1222x; 1.0504x over previous
//
#include <hip/hip_runtime.h>
#include <stdint.h>

typedef __attribute__((ext_vector_type(8))) short s16x8;
typedef __attribute__((ext_vector_type(4))) float f32x4;

#define GLD_LDS16(gp, lp) __builtin_amdgcn_global_load_lds( \
    (__attribute__((address_space(1))) void*)(void*)(gp), \
    (__attribute__((address_space(3))) void*)(lp), 16, 0, 0)

__device__ __forceinline__ float b2f(unsigned short s) {
    unsigned int u = ((unsigned int)s) << 16;
    return __builtin_bit_cast(float, u);
}
__device__ __forceinline__ unsigned short f2b(float f) {
    unsigned int u = __builtin_bit_cast(unsigned int, f);
    u = (u + 0x7FFFu + ((u >> 16) & 1u)) >> 16;
    return (unsigned short)u;
}
__device__ __forceinline__ f32x4 mfma16(s16x8 a, s16x8 b, f32x4 c) {
    return __builtin_amdgcn_mfma_f32_16x16x32_bf16(a, b, c, 0, 0, 0);
}

// ---------------- RMSNorm (fp32 in -> bf16 out), D = 2048 ----------------
__global__ __launch_bounds__(256) void rmsnorm_bf16(
    const float* __restrict__ x, const float* __restrict__ wgt,
    unsigned short* __restrict__ out)
{
    const int row = blockIdx.x;
    const int t = threadIdx.x;
    const float* xr = x + (size_t)row * 2048;
    float4 a = *(const float4*)(xr + t * 8);
    float4 b = *(const float4*)(xr + t * 8 + 4);
    float ss = a.x*a.x + a.y*a.y + a.z*a.z + a.w*a.w
             + b.x*b.x + b.y*b.y + b.z*b.z + b.w*b.w;
    #pragma unroll
    for (int d = 1; d < 64; d <<= 1) ss += __shfl_xor(ss, d);
    __shared__ float red[4];
    if ((t & 63) == 0) red[t >> 6] = ss;
    __syncthreads();
    float tot = red[0] + red[1] + red[2] + red[3];
    float inv = rsqrtf(tot * (1.0f / 2048.0f) + 1e-5f);
    float vals[8] = {a.x, a.y, a.z, a.w, b.x, b.y, b.z, b.w};
    const float* wr_ = wgt + t * 8;
    s16x8 ov;
    #pragma unroll
    for (int j = 0; j < 8; ++j) ov[j] = (short)f2b(vals[j] * inv * wr_[j]);
    *(s16x8*)(out + (size_t)row * 2048 + t * 8) = ov;
}

// ------------- transpose + convert: in fp32 [K][N] -> out bf16 [N][K] -------------
__global__ __launch_bounds__(256) void transpose_to_bf16(
    const float* __restrict__ in, unsigned short* __restrict__ out, int K, int N)
{
    __shared__ float tile[32][33];
    int n0 = blockIdx.x * 32, k0 = blockIdx.y * 32;
    int r = threadIdx.x >> 5, c = threadIdx.x & 31;
    #pragma unroll
    for (int i = 0; i < 4; ++i)
        tile[r + i * 8][c] = in[(size_t)(k0 + r + i * 8) * N + n0 + c];
    __syncthreads();
    #pragma unroll
    for (int i = 0; i < 4; ++i)
        out[(size_t)(n0 + r + i * 8) * K + k0 + c] = f2b(tile[c][r + i * 8]);
}

// ---------------- 8-phase GEMM: C[4096,N] = A[4096,K](bf16) * B[N,K]^T(bf16) ----------------
// Tile BM x 256, BK=64 as two K-half sub-tiles [rows][32]; 4 slots per operand,
// 3-deep prefetch with counted vmcnt. LDS chunk-XOR swizzle (T2, both-sides):
// physical 16B-chunk p = c ^ ((row>>1)&3); staging pre-swizzles the GLOBAL source
// column (LDS dest stays linear for global_load_lds), reads XOR with (l15>>1)&3.
// Wave grid 2M x 4N. EPI 0: C bf16.  EPI 1: C fp32 = acc+ADD.  EPI 2: C bf16 = silu(acc)*C_prev.
template <int BM, int EPI>
__global__ __launch_bounds__(512, 2) void gemm8p(
    const unsigned short* __restrict__ A,
    const unsigned short* __restrict__ B,
    void* __restrict__ Cv,
    const float* __restrict__ ADD,
    int N, int K)
{
    constexpr int MT = 4096 / BM;                 // M tiles
    constexpr int MI = BM / 32;                   // per-wave M fragments (4 or 8)
    constexpr int ASUB = BM * 32;                 // elems per A sub-tile
    constexpr int BSUB = 256 * 32;
    __shared__ __align__(16) unsigned short As[4 * ASUB];
    __shared__ __align__(16) unsigned short Bs[4 * BSUB];

    const int t = threadIdx.x;
    const int l = t & 63, w = t >> 6;
    const int l15 = l & 15, lg = l >> 4;
    const int wr = w >> 2, wc = w & 3;
    const int sx = (l15 >> 1) & 3;                // fragment-read chunk XOR

    // bijective XCD-aware block swizzle (m204)
    const int nwg = (int)gridDim.x;
    const int orig = (int)blockIdx.x;
    const int q8 = nwg >> 3, r8 = nwg & 7;
    const int xcd = orig & 7, lid = orig >> 3;
    const int wg = (xcd < r8 ? xcd * (q8 + 1) : r8 * (q8 + 1) + (xcd - r8) * q8) + lid;
    const int m0 = (wg % MT) * BM;
    const int n0 = (wg / MT) * 256;

    f32x4 acc[MI][4] = {};

    int aoff[MI], boff[4];
    #pragma unroll
    for (int i = 0; i < MI; ++i)
        aoff[i] = (wr * (BM / 2) + i * 16 + l15) * 32 + (lg ^ sx) * 8;
    #pragma unroll
    for (int j = 0; j < 4; ++j)
        boff[j] = (wc * 64 + j * 16 + l15) * 32 + (lg ^ sx) * 8;

    // staging: thread t fills LDS linearly at t*16B = (row=t>>2, physical chunk t&3);
    // pre-swizzle the global source column so read-side XOR matches (rule #21).
    const int srow = t >> 2;
    const int scol = ((t & 3) ^ ((t >> 3) & 3)) * 8;

    auto stage = [&](int slot, int koff) {
        #pragma unroll
        for (int q2 = 0; q2 < BM / 128; ++q2)
            GLD_LDS16(A + (size_t)(m0 + q2 * 128 + srow) * K + koff + scol,
                      &As[slot * ASUB + q2 * 4096 + t * 8]);
        #pragma unroll
        for (int q2 = 0; q2 < 2; ++q2)
            GLD_LDS16(B + (size_t)(n0 + q2 * 128 + srow) * K + koff + scol,
                      &Bs[slot * BSUB + q2 * 4096 + t * 8]);
    };
    auto waitv = [&]() {
        if constexpr (BM == 256) asm volatile("s_waitcnt vmcnt(8)" ::: "memory");
        else                     asm volatile("s_waitcnt vmcnt(6)" ::: "memory");
    };

    // prologue: slots 0,1,2 <- phase 0,1,2 data; wait for slot 0 only
    stage(0, 0); stage(1, 32); stage(2, 64);
    waitv();
    __builtin_amdgcn_s_barrier();

    const int PH = K / 32;
    const int kmax = K - 32;

    for (int p0 = 0; p0 < PH; p0 += 4) {
        #pragma unroll
        for (int pp = 0; pp < 4; ++pp) {
            const int sR = pp, sW = (pp + 3) & 3;
            int kW = (p0 + pp + 3) * 32; if (kW > kmax) kW = kmax;  // tail: dummy reload
            s16x8 af[MI], bfv[4];
            #pragma unroll
            for (int i = 0; i < MI; ++i)
                af[i] = *(const s16x8*)&As[sR * ASUB + aoff[i]];
            #pragma unroll
            for (int j = 0; j < 4; ++j)
                bfv[j] = *(const s16x8*)&Bs[sR * BSUB + boff[j]];
            stage(sW, kW);
            waitv();                                   // retire data for next phase
            asm volatile("s_waitcnt lgkmcnt(0)" ::: "memory");
            __builtin_amdgcn_sched_barrier(0);
            __builtin_amdgcn_s_setprio(1);
            #pragma unroll
            for (int i = 0; i < MI; ++i)
                #pragma unroll
                for (int j = 0; j < 4; ++j)
                    acc[i][j] = mfma16(af[i], bfv[j], acc[i][j]);
            __builtin_amdgcn_s_setprio(0);
            __builtin_amdgcn_sched_barrier(0);
            __builtin_amdgcn_s_barrier();
        }
    }

    #pragma unroll
    for (int i = 0; i < MI; ++i) {
        #pragma unroll
        for (int r = 0; r < 4; ++r) {
            const int row = m0 + wr * (BM / 2) + i * 16 + lg * 4 + r;
            const size_t rb = (size_t)row * N;
            #pragma unroll
            for (int j = 0; j < 4; ++j) {
                const int col = n0 + wc * 64 + j * 16 + l15;
                float v = acc[i][j][r];
                if constexpr (EPI == 0) {
                    ((unsigned short*)Cv)[rb + col] = f2b(v);
                } else if constexpr (EPI == 1) {
                    ((float*)Cv)[rb + col] = v + ADD[rb + col];
                } else {
                    unsigned short* Cb = (unsigned short*)Cv;
                    float y = b2f(Cb[rb + col]);
                    float sg = v / (1.0f + expf(-v));
                    Cb[rb + col] = f2b(sg * y);
                }
            }
        }
    }
}

// ---------------- RoPE table: [S][32] of (cos, sin) ----------------
__global__ void rope_tab_k(float2* __restrict__ tab) {
    int i = blockIdx.x * 256 + threadIdx.x;
    if (i >= 4096 * 32) return;
    int s = i >> 5, d = i & 31;
    float inv = exp2f(-(float)d * (13.287712379549449f / 32.0f));
    float fr = (float)s * inv;
    float sv, cv;
    sincosf(fr, &sv, &cv);
    tab[i] = make_float2(cv, sv);
}

// ---------------- RoPE apply (in-place on qkv, q heads + k heads) ----------------
__global__ void rope_apply_k(unsigned short* __restrict__ qkv, const float2* __restrict__ tab) {
    int i = blockIdx.x * 256 + threadIdx.x;
    if (i >= 4096 * 40 * 4) return;
    int dg = i & 3;
    int rest = i >> 2;
    int head = rest % 40;
    int s = rest / 40;
    int off = head < 32 ? head * 64 : 2048 + (head - 32) * 64;
    unsigned short* p = qkv + (size_t)s * 3072 + off + dg * 8;
    s16x8 x1 = *(const s16x8*)p;
    s16x8 x2 = *(const s16x8*)(p + 32);
    const float2* tb = tab + s * 32 + dg * 8;
    s16x8 o1, o2;
    #pragma unroll
    for (int j = 0; j < 8; ++j) {
        float2 cs = tb[j];
        float a = b2f((unsigned short)x1[j]);
        float b = b2f((unsigned short)x2[j]);
        o1[j] = (short)f2b(a * cs.x - b * cs.y);
        o2[j] = (short)f2b(b * cs.x + a * cs.y);
    }
    *(s16x8*)p = o1;
    *(s16x8*)(p + 32) = o2;
}

// ---------------- Sliding-window attention, flash-style ----------------
__global__ __launch_bounds__(256) void attn_swa(
    const unsigned short* __restrict__ qkv,
    unsigned short* __restrict__ out)
{
    constexpr int LDQ = 3072;
    const int qb = blockIdx.x;
    const int h = blockIdx.y;
    const int kvh = h >> 2;
    const int q0 = qb * 64;
    const int t = threadIdx.x, l = t & 63, w = t >> 6;
    const int l15 = l & 15, lg = l >> 4;

    __shared__ unsigned short Kl[64 * 64];
    __shared__ unsigned short Vt[64 * 72];
    __shared__ unsigned short Pl[4 * 16 * 72];

    s16x8 qf[2];
    {
        const unsigned short* qp = qkv + (size_t)(q0 + w * 16 + l15) * LDQ + h * 64 + lg * 8;
        qf[0] = *(const s16x8*)(qp);
        qf[1] = *(const s16x8*)(qp + 32);
    }
    float m_run[4] = {-1e30f, -1e30f, -1e30f, -1e30f};
    float l_run[4] = {0.f, 0.f, 0.f, 0.f};
    f32x4 o[4] = {};

    const float SC = 0.0625f * 1.4426950408889634f;
    const int kt_lo = qb >= 8 ? qb - 8 : 0;

    for (int kt = kt_lo; kt <= qb; ++kt) {
        const int ks = kt * 64;
        __syncthreads();
        {
            const unsigned short* kg = qkv + (size_t)(ks + (t >> 3)) * LDQ + 2048 + kvh * 64 + (t & 7) * 8;
            GLD_LDS16(kg, Kl + t * 8);
            GLD_LDS16(kg + (size_t)32 * LDQ, Kl + t * 8 + 2048);
        }
        {
            const unsigned short* vg = qkv + (size_t)(ks + l) * LDQ + 2560 + kvh * 64 + w * 16;
            s16x8 v0 = *(const s16x8*)vg;
            s16x8 v1 = *(const s16x8*)(vg + 8);
            #pragma unroll
            for (int j = 0; j < 8; ++j) Vt[(w * 16 + j) * 72 + l] = (unsigned short)v0[j];
            #pragma unroll
            for (int j = 0; j < 8; ++j) Vt[(w * 16 + 8 + j) * 72 + l] = (unsigned short)v1[j];
        }
        __syncthreads();

        f32x4 sf[4] = {};
        #pragma unroll
        for (int kf = 0; kf < 4; ++kf) {
            #pragma unroll
            for (int kk = 0; kk < 2; ++kk) {
                s16x8 kb = *(const s16x8*)(Kl + (kf * 16 + l15) * 64 + kk * 32 + lg * 8);
                sf[kf] = mfma16(qf[kk], kb, sf[kf]);
            }
        }

        float tmax[4];
        #pragma unroll
        for (int r = 0; r < 4; ++r) {
            int qrow = q0 + w * 16 + lg * 4 + r;
            float mx = -1e30f;
            #pragma unroll
            for (int kf = 0; kf < 4; ++kf) {
                int key = ks + kf * 16 + l15;
                bool valid = (key <= qrow) && (qrow - key < 512);
                if (valid) mx = fmaxf(mx, sf[kf][r]);
            }
            #pragma unroll
            for (int d2 = 1; d2 < 16; d2 <<= 1) mx = fmaxf(mx, __shfl_xor(mx, d2));
            tmax[r] = mx;
        }

        float alpha[4], rsum[4];
        #pragma unroll
        for (int r = 0; r < 4; ++r) {
            float mnew = fmaxf(m_run[r], tmax[r]);
            alpha[r] = exp2f((m_run[r] - mnew) * SC);
            m_run[r] = mnew;
            rsum[r] = 0.f;
        }

        unsigned short* Pw = Pl + w * (16 * 72);
        #pragma unroll
        for (int kf = 0; kf < 4; ++kf) {
            #pragma unroll
            for (int r = 0; r < 4; ++r) {
                int qrow = q0 + w * 16 + lg * 4 + r;
                int key = ks + kf * 16 + l15;
                bool valid = (key <= qrow) && (qrow - key < 512);
                float p = valid ? exp2f((sf[kf][r] - m_run[r]) * SC) : 0.f;
                rsum[r] += p;
                Pw[(lg * 4 + r) * 72 + kf * 16 + l15] = f2b(p);
            }
        }
        #pragma unroll
        for (int r = 0; r < 4; ++r) {
            #pragma unroll
            for (int d2 = 1; d2 < 16; d2 <<= 1) rsum[r] += __shfl_xor(rsum[r], d2);
            l_run[r] = l_run[r] * alpha[r] + rsum[r];
        }
        #pragma unroll
        for (int hf = 0; hf < 4; ++hf)
            #pragma unroll
            for (int r = 0; r < 4; ++r) o[hf][r] *= alpha[r];

        asm volatile("s_waitcnt lgkmcnt(0)" ::: "memory");
        __builtin_amdgcn_sched_barrier(0);

        #pragma unroll
        for (int kk2 = 0; kk2 < 2; ++kk2) {
            s16x8 pa = *(const s16x8*)(Pw + l15 * 72 + kk2 * 32 + lg * 8);
            #pragma unroll
            for (int hf = 0; hf < 4; ++hf) {
                s16x8 vb = *(const s16x8*)(Vt + (hf * 16 + l15) * 72 + kk2 * 32 + lg * 8);
                o[hf] = mfma16(pa, vb, o[hf]);
            }
        }
    }

    #pragma unroll
    for (int r = 0; r < 4; ++r) {
        int qrow = q0 + w * 16 + lg * 4 + r;
        float invl = 1.0f / l_run[r];
        unsigned short* orow = out + (size_t)qrow * 2048 + h * 64;
        #pragma unroll
        for (int hf = 0; hf < 4; ++hf)
            orow[hf * 16 + l15] = f2b(o[hf][r] * invl);
    }
}

extern "C" void kernel_launch(void* const* d_in, const int* in_sizes, int n_in,
                              void* d_out, int out_size, void* d_ws, size_t ws_size,
                              hipStream_t stream)
{
    const float* hidden = (const float*)d_in[0];
    const float* w_mix  = (const float*)d_in[1];
    const float* wq     = (const float*)d_in[2];
    const float* wk     = (const float*)d_in[3];
    const float* wv     = (const float*)d_in[4];
    const float* wo     = (const float*)d_in[5];
    const float* w_mlp  = (const float*)d_in[6];
    const float* wg     = (const float*)d_in[7];
    const float* wd     = (const float*)d_in[8];
    float* out = (float*)d_out;

    char* ws = (char*)d_ws;
    size_t off = 0;
    auto alloc = [&](size_t bytes) {
        char* p = ws + off;
        off += (bytes + 255) & ~(size_t)255;
        return p;
    };
    unsigned short* Wt   = (unsigned short*)alloc((size_t)11264 * 2048 * 2);
    unsigned short* xn   = (unsigned short*)alloc((size_t)4096 * 2048 * 2);
    unsigned short* qkv  = (unsigned short*)alloc((size_t)4096 * 3072 * 2);
    float2*         rtab = (float2*)alloc((size_t)4096 * 32 * 8);
    unsigned short* attn = (unsigned short*)alloc((size_t)4096 * 2048 * 2);
    float*          hbuf = (float*)alloc((size_t)4096 * 2048 * 4);
    unsigned short* act  = (unsigned short*)alloc((size_t)4096 * 5632 * 2);

    // 1. x = rmsnorm(hidden) -> bf16
    rmsnorm_bf16<<<4096, 256, 0, stream>>>(hidden, w_mix, xn);

    // 2. W^T for q,k,v concatenated
    transpose_to_bf16<<<dim3(64, 64), 256, 0, stream>>>(wq, Wt, 2048, 2048);
    transpose_to_bf16<<<dim3(16, 64), 256, 0, stream>>>(wk, Wt + (size_t)2048 * 2048, 2048, 512);
    transpose_to_bf16<<<dim3(16, 64), 256, 0, stream>>>(wv, Wt + (size_t)2560 * 2048, 2048, 512);

    // 3. qkv = x @ [wq|wk|wv]   (M=4096, N=3072, K=2048) BM=256 -> 192 blocks
    gemm8p<256, 0><<<192, 512, 0, stream>>>(xn, Wt, qkv, nullptr, 3072, 2048);

    // 4. RoPE
    rope_tab_k<<<(4096 * 32 + 255) / 256, 256, 0, stream>>>(rtab);
    rope_apply_k<<<(4096 * 40 * 4 + 255) / 256, 256, 0, stream>>>(qkv, rtab);

    // 5. sliding-window attention
    attn_swa<<<dim3(64, 32), 256, 0, stream>>>(qkv, attn);

    // 6. h = hidden + attn @ wo   (N=2048) BM=128 -> 256 blocks
    transpose_to_bf16<<<dim3(64, 64), 256, 0, stream>>>(wo, Wt, 2048, 2048);
    gemm8p<128, 1><<<256, 512, 0, stream>>>(attn, Wt, hbuf, hidden, 2048, 2048);

    // 7. xn2 = rmsnorm(h)
    rmsnorm_bf16<<<4096, 256, 0, stream>>>(hbuf, w_mlp, xn);

    // 8. MLP: act = y; act = silu(gate) * act   (N=5632) BM=128 -> 704 blocks
    transpose_to_bf16<<<dim3(352, 64), 256, 0, stream>>>(wg, Wt, 2048, 11264);
    gemm8p<128, 0><<<704, 512, 0, stream>>>(xn, Wt + (size_t)5632 * 2048, act, nullptr, 5632, 2048);
    gemm8p<128, 2><<<704, 512, 0, stream>>>(xn, Wt, act, nullptr, 5632, 2048);

    // 9. out = h + act @ w_down   (N=2048, K=5632) BM=128 -> 256 blocks
    transpose_to_bf16<<<dim3(64, 176), 256, 0, stream>>>(wd, Wt, 5632, 2048);
    gemm8p<128, 1><<<256, 512, 0, stream>>>(act, Wt, out, hbuf, 2048, 5632);
}